// Round 7
// baseline (312.110 us; speedup 1.0000x reference)
//
#include <hip/hip_runtime.h>

#define DIM     64
#define N_EMBED 512
#define N_ROWS  131072   // 32*64*64
#define XPAD    132      // row pitch (bank stagger); swizzle stays within [0,128)

// ---------- prep: ||e_j||^2 and (optional) embed transpose ----------
__global__ void prep_kernel(const float* __restrict__ embed,
                            float* __restrict__ se,
                            float* __restrict__ embed_t,
                            int do_et) {
    int j = blockIdx.x * blockDim.x + threadIdx.x;   // 0..511
    if (j >= N_EMBED) return;
    float s = 0.f;
#pragma unroll
    for (int d = 0; d < DIM; d += 4) {
        float b0 = embed[(d + 0) * N_EMBED + j];
        float b1 = embed[(d + 1) * N_EMBED + j];
        float b2 = embed[(d + 2) * N_EMBED + j];
        float b3 = embed[(d + 3) * N_EMBED + j];
        s = fmaf(b0, b0, s); s = fmaf(b1, b1, s);
        s = fmaf(b2, b2, s); s = fmaf(b3, b3, s);
        if (do_et) {
            float4 v; v.x = b0; v.y = b1; v.z = b2; v.w = b3;
            *reinterpret_cast<float4*>(&embed_t[j * DIM + d]) = v;
        }
    }
    se[j] = s;
}

// ---------- assign: LDS-tiled fp32 GEMM-argmin (unchanged from round 6) ----------
__launch_bounds__(256, 2)
__global__ void vq_assign(const float* __restrict__ input,
                          const float* __restrict__ embed,
                          const float* __restrict__ se,
                          float* __restrict__ out_ind,
                          int*   __restrict__ ind) {
    __shared__ float Xs[64][XPAD];   // [k][row]
    __shared__ float Es[64][XPAD];   // [k][swizzled col]; reused for final reduce
    __shared__ float sxs[128];

    const int t    = threadIdx.x;
    const int row0 = blockIdx.x * 128;
    const int tr   = t >> 4;   // 0..15
    const int tc   = t & 15;   // 0..15
    const int bx   = ((tc >> 2) & 1) * 4;   // bit5(tc*8) * 4, XOR on read

    // ---- stage X transposed: Xs[k][i] = input[(row0+i)*64 + k] ----
#pragma unroll
    for (int ph = 0; ph < 8; ++ph) {
        int idx = ph * 256 + t;      // 0..2047
        int row = idx >> 4;          // 0..127
        int kq  = idx & 15;          // 0..15
        float4 v = *reinterpret_cast<const float4*>(
            &input[(size_t)(row0 + row) * 64 + kq * 4]);
        Xs[kq * 4 + 0][row] = v.x;
        Xs[kq * 4 + 1][row] = v.y;
        Xs[kq * 4 + 2][row] = v.z;
        Xs[kq * 4 + 3][row] = v.w;
    }
    __syncthreads();

    // ---- sx per row ----
    if (t < 128) {
        float s = 0.f;
#pragma unroll 8
        for (int k = 0; k < 64; ++k) { float x = Xs[k][t]; s = fmaf(x, x, s); }
        sxs[t] = s;
    }

    float bestd[8], sx[8];
    int   bestj[8];
#pragma unroll
    for (int r = 0; r < 8; ++r) { bestd[r] = INFINITY; bestj[r] = 0; }

    for (int chunk = 0; chunk < 4; ++chunk) {
        const int ccb = chunk * 128;
        __syncthreads();   // prev k-loop done reading Es (also fences sxs/Xs)
#pragma unroll
        for (int ph = 0; ph < 8; ++ph) {
            int idx = ph * 256 + t;  // 0..2047
            int k   = idx >> 5;      // 0..63
            int cq  = idx & 31;      // 0..31
            float4 v = *reinterpret_cast<const float4*>(
                &embed[k * N_EMBED + ccb + cq * 4]);
            // XOR swizzle: block base c=cq*4 -> c ^ (bit5(c)*4)
            *reinterpret_cast<float4*>(&Es[k][(cq * 4) ^ (((cq >> 3) & 1) * 4)]) = v;
        }
        __syncthreads();
        if (chunk == 0) {
#pragma unroll
            for (int r = 0; r < 8; ++r) sx[r] = sxs[tr * 8 + r];
        }

        float acc[8][8];
#pragma unroll
        for (int r = 0; r < 8; ++r)
#pragma unroll
            for (int c = 0; c < 8; ++c) acc[r][c] = 0.f;

#pragma unroll 2
        for (int k = 0; k < 64; ++k) {
            float a[8], b[8];
            *reinterpret_cast<float4*>(&a[0]) = *reinterpret_cast<const float4*>(&Xs[k][tr * 8]);
            *reinterpret_cast<float4*>(&a[4]) = *reinterpret_cast<const float4*>(&Xs[k][tr * 8 + 4]);
            *reinterpret_cast<float4*>(&b[0]) = *reinterpret_cast<const float4*>(&Es[k][(tc * 8) ^ bx]);
            *reinterpret_cast<float4*>(&b[4]) = *reinterpret_cast<const float4*>(&Es[k][(tc * 8 + 4) ^ bx]);
#pragma unroll
            for (int r = 0; r < 8; ++r)
#pragma unroll
                for (int c = 0; c < 8; ++c)
                    acc[r][c] = fmaf(a[r], b[c], acc[r][c]);
        }

        // finalize this chunk: scan cols in increasing j (first-wins ties)
#pragma unroll
        for (int c = 0; c < 8; ++c) {
            int j = ccb + tc * 8 + c;
            float sej = se[j];
#pragma unroll
            for (int r = 0; r < 8; ++r) {
                float d = (sx[r] - 2.f * acc[r][c]) + sej;
                if (d < bestd[r]) { bestd[r] = d; bestj[r] = j; }
            }
        }
    }

    // ---- cross-thread argmin reduce (lexicographic (d, j) == global first-min) ----
    __syncthreads();
    float* rd = &Es[0][0];                 // [128][17]
    int*   rj = (int*)(rd + 128 * 17);     // [128][17]
#pragma unroll
    for (int r = 0; r < 8; ++r) {
        rd[(tr * 8 + r) * 17 + tc] = bestd[r];
        rj[(tr * 8 + r) * 17 + tc] = bestj[r];
    }
    __syncthreads();
    if (t < 128) {
        float bd = rd[t * 17 + 0];
        int   bj = rj[t * 17 + 0];
#pragma unroll
        for (int w = 1; w < 16; ++w) {
            float dw = rd[t * 17 + w];
            int   jw = rj[t * 17 + w];
            if (dw < bd || (dw == bd && jw < bj)) { bd = dw; bj = jw; }
        }
        out_ind[row0 + t] = (float)bj;
        ind[row0 + t]     = bj;
    }
}

// ---------- post (partials): quantize + diff + LDS segment-sum, plain-store flush ----------
__launch_bounds__(512, 1)
__global__ void vq_post_p(const float* __restrict__ input,
                          const float* __restrict__ embed_t,
                          const int* __restrict__ ind,
                          float* __restrict__ out_q,
                          float* __restrict__ partials,
                          float* __restrict__ counts,
                          double* __restrict__ diff_acc,
                          int niter) {
    __shared__ float lesum[DIM * N_EMBED];   // 128 KB
    __shared__ float lcount[N_EMBED];
    __shared__ float wsum[8];
    const int t = threadIdx.x;

    float4* l4 = reinterpret_cast<float4*>(lesum);
#pragma unroll
    for (int i = 0; i < 16; ++i) l4[t + i * 512] = float4{0.f, 0.f, 0.f, 0.f};
    lcount[t] = 0.f;
    __syncthreads();

    float dsum = 0.f;
    for (int it = 0; it < niter; ++it) {
        const int row = (blockIdx.x * niter + it) * 512 + t;
        const int j = ind[row];
        atomicAdd(&lcount[j], 1.0f);
        const float* rp = input + (size_t)row * DIM;
        const float* qp = embed_t + (size_t)j * DIM;
        float* oq = out_q + (size_t)row * DIM;
#pragma unroll
        for (int d = 0; d < DIM; d += 4) {
            float4 v = *reinterpret_cast<const float4*>(rp + d);
            float4 q = *reinterpret_cast<const float4*>(qp + d);
            float t0 = q.x - v.x, t1 = q.y - v.y, t2 = q.z - v.z, t3 = q.w - v.w;
            float4 o;
            o.x = v.x + t0; o.y = v.y + t1; o.z = v.z + t2; o.w = v.w + t3;
            *reinterpret_cast<float4*>(oq + d) = o;
            dsum = fmaf(t0, t0, dsum); dsum = fmaf(t1, t1, dsum);
            dsum = fmaf(t2, t2, dsum); dsum = fmaf(t3, t3, dsum);
            atomicAdd(&lesum[(d + 0) * N_EMBED + j], v.x);
            atomicAdd(&lesum[(d + 1) * N_EMBED + j], v.y);
            atomicAdd(&lesum[(d + 2) * N_EMBED + j], v.z);
            atomicAdd(&lesum[(d + 3) * N_EMBED + j], v.w);
        }
    }
    __syncthreads();

    // plain coalesced flush to this block's partial copy
    float* dst = partials + (size_t)blockIdx.x * (DIM * N_EMBED);
    for (int i = t * 4; i < DIM * N_EMBED; i += 2048) {
        *reinterpret_cast<float4*>(dst + i) = *reinterpret_cast<float4*>(&lesum[i]);
    }
    {
        float v = lcount[t];
        if (v != 0.f) atomicAdd(&counts[t], v);
    }

    // diff: wave -> block reduce, one f64 atomic per block
    for (int off = 32; off > 0; off >>= 1) dsum += __shfl_down(dsum, off, 64);
    int lane = t & 63, wid = t >> 6;
    if (lane == 0) wsum[wid] = dsum;
    __syncthreads();
    if (t == 0) {
        float b = 0.f;
#pragma unroll
        for (int w = 0; w < 8; ++w) b += wsum[w];
        atomicAdd(diff_acc, (double)b);
    }
}

// ---------- post (fallback): original atomic-flush version ----------
__launch_bounds__(512, 1)
__global__ void vq_post(const float* __restrict__ input,
                        const float* __restrict__ embed,
                        const float* __restrict__ embed_t,
                        const int* __restrict__ ind,
                        float* __restrict__ out_q,
                        float* __restrict__ esum,
                        float* __restrict__ counts,
                        double* __restrict__ diff_acc,
                        int have_et) {
    __shared__ float lesum[DIM * N_EMBED];   // 128 KB
    __shared__ float lcount[N_EMBED];
    __shared__ float wsum[8];
    const int t = threadIdx.x;

    float4* l4 = reinterpret_cast<float4*>(lesum);
#pragma unroll
    for (int i = 0; i < 16; ++i) l4[t + i * 512] = float4{0.f, 0.f, 0.f, 0.f};
    lcount[t] = 0.f;
    __syncthreads();

    const int row = blockIdx.x * 512 + t;    // one row per thread
    const int j = ind[row];
    atomicAdd(&lcount[j], 1.0f);
    const float* rp = input + (size_t)row * DIM;
    float* oq = out_q + (size_t)row * DIM;
    float dsum = 0.f;

    if (have_et) {
        const float* qp = embed_t + (size_t)j * DIM;
#pragma unroll
        for (int d = 0; d < DIM; d += 4) {
            float4 v = *reinterpret_cast<const float4*>(rp + d);
            float4 q = *reinterpret_cast<const float4*>(qp + d);
            float t0 = q.x - v.x, t1 = q.y - v.y, t2 = q.z - v.z, t3 = q.w - v.w;
            float4 o;
            o.x = v.x + t0; o.y = v.y + t1; o.z = v.z + t2; o.w = v.w + t3;
            *reinterpret_cast<float4*>(oq + d) = o;
            dsum = fmaf(t0, t0, dsum); dsum = fmaf(t1, t1, dsum);
            dsum = fmaf(t2, t2, dsum); dsum = fmaf(t3, t3, dsum);
            atomicAdd(&lesum[(d + 0) * N_EMBED + j], v.x);
            atomicAdd(&lesum[(d + 1) * N_EMBED + j], v.y);
            atomicAdd(&lesum[(d + 2) * N_EMBED + j], v.z);
            atomicAdd(&lesum[(d + 3) * N_EMBED + j], v.w);
        }
    } else {
#pragma unroll
        for (int d = 0; d < DIM; d += 4) {
            float4 v = *reinterpret_cast<const float4*>(rp + d);
            float q0 = embed[(d + 0) * N_EMBED + j];
            float q1 = embed[(d + 1) * N_EMBED + j];
            float q2 = embed[(d + 2) * N_EMBED + j];
            float q3 = embed[(d + 3) * N_EMBED + j];
            float t0 = q0 - v.x, t1 = q1 - v.y, t2 = q2 - v.z, t3 = q3 - v.w;
            float4 o;
            o.x = v.x + t0; o.y = v.y + t1; o.z = v.z + t2; o.w = v.w + t3;
            *reinterpret_cast<float4*>(oq + d) = o;
            dsum = fmaf(t0, t0, dsum); dsum = fmaf(t1, t1, dsum);
            dsum = fmaf(t2, t2, dsum); dsum = fmaf(t3, t3, dsum);
            atomicAdd(&lesum[(d + 0) * N_EMBED + j], v.x);
            atomicAdd(&lesum[(d + 1) * N_EMBED + j], v.y);
            atomicAdd(&lesum[(d + 2) * N_EMBED + j], v.z);
            atomicAdd(&lesum[(d + 3) * N_EMBED + j], v.w);
        }
    }
    __syncthreads();

    for (int i = t; i < DIM * N_EMBED; i += 512) {
        float v = lesum[i];
        if (v != 0.f) atomicAdd(&esum[i], v);
    }
    {
        float v = lcount[t];
        if (v != 0.f) atomicAdd(&counts[t], v);
    }

    for (int off = 32; off > 0; off >>= 1) dsum += __shfl_down(dsum, off, 64);
    int lane = t & 63, wid = t >> 6;
    if (lane == 0) wsum[wid] = dsum;
    __syncthreads();
    if (t == 0) {
        float b = 0.f;
#pragma unroll
        for (int w = 0; w < 8; ++w) b += wsum[w];
        atomicAdd(diff_acc, (double)b);
    }
}

// ---------- finalize A: new_cluster_size + n ----------
__global__ void fin_a(const float* __restrict__ cluster_size,
                      const float* __restrict__ counts,
                      float* __restrict__ out_ncs,
                      float* __restrict__ nstore) {
    int t = threadIdx.x;  // 512 threads, 1 block
    float ncs = cluster_size[t] * 0.99f + 0.01f * counts[t];
    out_ncs[t] = ncs;
    __shared__ float red[512];
    red[t] = ncs;
    __syncthreads();
    for (int s = 256; s > 0; s >>= 1) {
        if (t < s) red[t] += red[t + s];
        __syncthreads();
    }
    if (t == 0) nstore[0] = red[0];
}

// ---------- finalize B: fused partial-reduce + EMA + normalize + diff ----------
__global__ void fin_b(const float* __restrict__ embed_avg,
                      const float* __restrict__ src,   // partials (npart copies) or esum (npart=1)
                      int npart,
                      const float* __restrict__ out_ncs,
                      const float* __restrict__ nstore,
                      const double* __restrict__ diff_acc,
                      float* __restrict__ out_ne,
                      float* __restrict__ out_nea,
                      float* __restrict__ out_diff) {
    int e = blockIdx.x * 512 + threadIdx.x;   // 64 blocks -> 32768
    const float EPSF = 1e-5f;
    float s = 0.f;
    for (int p = 0; p < npart; ++p) s += src[(size_t)p * (DIM * N_EMBED) + e];
    float n = nstore[0];
    int j = e & (N_EMBED - 1);
    float ncs = out_ncs[j];
    float cs = (ncs + EPSF) / (n + 512.0f * EPSF) * n;
    float es = embed_avg[e] * 0.99f + 0.01f * s;
    out_nea[e] = es;
    out_ne[e] = es / cs;
    if (e == 0) out_diff[0] = (float)(*diff_acc * (1.0 / 8388608.0));
}

extern "C" void kernel_launch(void* const* d_in, const int* in_sizes, int n_in,
                              void* d_out, int out_size, void* d_ws, size_t ws_size,
                              hipStream_t stream) {
    const float* input        = (const float*)d_in[0];
    const float* embed        = (const float*)d_in[1];
    const float* cluster_size = (const float*)d_in[2];
    const float* embed_avg    = (const float*)d_in[3];

    float* out_q    = (float*)d_out;          // 8388608 floats
    float* out_diff = out_q + 8388608;        // 1
    float* out_ind  = out_diff + 1;           // 131072
    float* out_ne   = out_ind + 131072;       // 32768
    float* out_ncs  = out_ne + 32768;         // 512
    float* out_nea  = out_ncs + 512;          // 32768

    // ws layout
    char*   ws       = (char*)d_ws;
    double* diff_acc = (double*)ws;                              // [0,8)
    float*  nstore   = (float*)(ws + 64);                        // 1 f32
    float*  counts   = (float*)(ws + 256);                       // 512 f32
    float*  se       = (float*)(ws + 4096);                      // 512 f32
    int*    ind      = (int*)(ws + 8192);                        // 131072 i32 (512 KB)
    float*  esum     = (float*)(ws + 8192 + 524288);             // 32768 f32 (128 KB)
    float*  embed_t  = (float*)(ws + 8192 + 524288 + 131072);    // 32768 f32 (128 KB)
    float*  partials = (float*)(ws + (1 << 20));                 // npart * 128 KB

    const size_t POFF = 1 << 20;
    int npart = 0, niter = 0;
    if (ws_size >= POFF + (size_t)256 * 131072)      { npart = 256; niter = 1; }
    else if (ws_size >= POFF + (size_t)64 * 131072)  { npart = 64;  niter = 4; }
    const size_t need_et = 8192 + 524288 + 131072 + 131072;
    const int have_et = (ws_size >= need_et) ? 1 : 0;

    hipMemsetAsync(ws, 0, 4096, stream);   // diff_acc + nstore + counts

    if (npart && have_et) {
        prep_kernel<<<2, 256, 0, stream>>>(embed, se, embed_t, 1);
        vq_assign<<<1024, 256, 0, stream>>>(input, embed, se, out_ind, ind);
        vq_post_p<<<npart, 512, 0, stream>>>(input, embed_t, ind, out_q, partials,
                                             counts, diff_acc, niter);
        fin_a<<<1, 512, 0, stream>>>(cluster_size, counts, out_ncs, nstore);
        fin_b<<<64, 512, 0, stream>>>(embed_avg, partials, npart, out_ncs, nstore,
                                      diff_acc, out_ne, out_nea, out_diff);
    } else {
        hipMemsetAsync(ws + 8192 + 524288, 0, 131072, stream); // esum
        prep_kernel<<<2, 256, 0, stream>>>(embed, se, embed_t, have_et);
        vq_assign<<<1024, 256, 0, stream>>>(input, embed, se, out_ind, ind);
        vq_post<<<256, 512, 0, stream>>>(input, embed, embed_t, ind, out_q, esum,
                                         counts, diff_acc, have_et);
        fin_a<<<1, 512, 0, stream>>>(cluster_size, counts, out_ncs, nstore);
        fin_b<<<64, 512, 0, stream>>>(embed_avg, esum, 1, out_ncs, nstore,
                                      diff_acc, out_ne, out_nea, out_diff);
    }
}